// Round 5
// baseline (351.062 us; speedup 1.0000x reference)
//
#include <hip/hip_runtime.h>

// ---------------- problem constants ----------------
#define N_ANCH 221184      // H*W*A = 128*192*9
#define HW     24576       // H*W
#define Wd     192
#define AA     9
#define TOPN   6000
#define POSTN  300
#define CAND_CAP 8192
#define NWORDS 94          // ceil(6016/64) words of suppression bits
#define NCHUNK 47          // 6016 / 128

typedef unsigned long long u64;

// anchor widths/heights (== ws2/hs2 of the reference, exact small ints)
// ratio 0.5: 23x12 -> w {184,368,736}, h { 96,192,384}
// ratio 1.0: 16x16 -> w {128,256,512}, h {128,256,512}
// ratio 2.0: 11x22 -> w { 88,176,352}, h {176,352,704}
__device__ const float c_aw[9] = {184.f,368.f,736.f,128.f,256.f,512.f, 88.f,176.f,352.f};
__device__ const float c_ah[9] = { 96.f,192.f,384.f,128.f,256.f,512.f,176.f,352.f,704.f};

// shared box decode — used by decode_kernel AND rank_scatter so the FP
// sequence (and thus every bit of the box) is identical in both places.
// No-FMA contraction to match numpy's separate mul/add rounding.
__device__ __forceinline__ float4 decode_box(int a, int cell,
                                             const float* __restrict__ deltas,
                                             float info0, float info1, float info2,
                                             bool* valid) {
    int h = cell / Wd;
    int w = cell - h * Wd;
    const float* db = deltas + (size_t)(4 * a) * HW + cell;
    float dx = db[0];
    float dy = db[HW];
    float dw = db[2 * HW];
    float dh = db[3 * HW];
    dw = fminf(fmaxf(dw, -10.f), 10.f);
    dh = fminf(fmaxf(dh, -10.f), 10.f);

    float ww = c_aw[a], hh = c_ah[a];
    float cx = 16.f * (float)w + 8.f;   // exact
    float cy = 16.f * (float)h + 8.f;   // exact

    float pcx = __fadd_rn(__fmul_rn(dx, ww), cx);
    float pcy = __fadd_rn(__fmul_rn(dy, hh), cy);
    float pw  = __fmul_rn(expf(dw), ww);
    float ph  = __fmul_rn(expf(dh), hh);
    float hpw = __fmul_rn(0.5f, pw);
    float hph = __fmul_rn(0.5f, ph);
    float x1 = __fsub_rn(pcx, hpw);
    float x2 = __fadd_rn(pcx, hpw);
    float y1 = __fsub_rn(pcy, hph);
    float y2 = __fadd_rn(pcy, hph);

    float xmax = __fsub_rn(info1, 1.f);
    float ymax = __fsub_rn(info0, 1.f);
    x1 = fminf(fmaxf(x1, 0.f), xmax);
    x2 = fminf(fmaxf(x2, 0.f), xmax);
    y1 = fminf(fmaxf(y1, 0.f), ymax);
    y2 = fminf(fmaxf(y2, 0.f), ymax);

    float msz = __fmul_rn(16.f, info2);
    *valid = (__fadd_rn(__fsub_rn(x2, x1), 1.f) >= msz) &&
             (__fadd_rn(__fsub_rn(y2, y1), 1.f) >= msz);
    return make_float4(x1, y1, x2, y2);
}

// ---------------- init: zero hist16+state+cand (contiguous) + vmask --------
#define ZA_F4 20484   // (262144 + 64 + 65536) / 16
#define ZB_F4 48      // 768 / 16
__global__ __launch_bounds__(256) void init_kernel(float4* zA, float4* zB) {
    int t = blockIdx.x * 256 + threadIdx.x;
    float4 z = make_float4(0.f, 0.f, 0.f, 0.f);
    if (t < ZA_F4) zA[t] = z;
    else if (t < ZA_F4 + ZB_F4) zB[t - ZA_F4] = z;
}

// thread t maps to (a = t/HW, cell = t%HW) so reads of scores/deltas are
// coalesced. Writes only the 32-bit ordered key; builds the 16-bit-prefix
// histogram directly with global atomics (bins max ~900 entries).
__global__ __launch_bounds__(256) void decode_kernel(const float* __restrict__ scores,
                                                     const float* __restrict__ deltas,
                                                     const float* __restrict__ iminfo,
                                                     unsigned int* __restrict__ keys,
                                                     unsigned int* __restrict__ hist16) {
    int t = blockIdx.x * 256 + threadIdx.x;
    int a = t / HW;
    int cell = t - a * HW;
    float score = scores[(AA + a) * HW + cell];
    bool valid;
    (void)decode_box(a, cell, deltas, iminfo[0], iminfo[1], iminfo[2], &valid);
    unsigned int sb = __float_as_uint(score);
    // flip to ordered-uint; invalid -> key of -inf (0x007FFFFF)
    unsigned int key = valid ? ((sb & 0x80000000u) ? ~sb : (sb | 0x80000000u))
                             : 0x007FFFFFu;
    keys[t] = key;
    atomicAdd(&hist16[key >> 16], 1u);
}

// one block: suffix-sum the 65536-bin histogram, pick the largest 16-bit
// bucket x* with count(key>=x*<<16) >= TOPN. state[0] = threshold.
__global__ __launch_bounds__(1024) void select16_kernel(const unsigned int* __restrict__ hist,
                                                        unsigned int* __restrict__ state) {
    __shared__ unsigned int ssum[1024];
    int t = threadIdx.x;
    unsigned int local = 0;
    for (int i = 0; i < 64; ++i) local += hist[t * 64 + i];
    ssum[t] = local;
    __syncthreads();
    for (int d = 1; d < 1024; d <<= 1) {
        unsigned int v = (t + d < 1024) ? ssum[t + d] : 0u;
        __syncthreads();
        ssum[t] += v;
        __syncthreads();
    }
    unsigned int ge = ssum[t];
    unsigned int gt = (t < 1023) ? ssum[t + 1] : 0u;
    if (ge >= TOPN && gt < TOPN) {
        unsigned int running = gt;
        for (int i = 63; i >= 0; --i) {
            running += hist[t * 64 + i];
            if (running >= TOPN) { state[0] = ((unsigned int)(t * 64 + i)) << 16; break; }
        }
    }
}

// take all keys >= T (boundary bucket fully included; cc ~6000+bucket < 8192)
__global__ __launch_bounds__(256) void compact_kernel(const unsigned int* __restrict__ keys,
                                                      unsigned int* __restrict__ state,
                                                      u64* __restrict__ cand) {
    int t = blockIdx.x * 256 + threadIdx.x;
    unsigned int k = keys[t];
    unsigned int T = state[0];
    if (k >= T) {
        unsigned int pos = atomicAdd(&state[2], 1u);
        if (pos < CAND_CAP) {
            int a = t / HW;
            int cell = t - a * HW;
            unsigned int aidx = (unsigned int)(cell * 9 + a);  // reference anchor index
            cand[pos] = ((u64)k << 32) | (u64)(~aidx);
        }
    }
}

// fused exact-rank + scatter. rank[i] = #{j : key_j > key_i}; keys distinct
// (index in low bits) -> rank == sorted position (score desc, index asc —
// lax.top_k order). Each block stages all 8192 cand in LDS; 2 threads/i
// split the j-range; winner recomputes its box from deltas and scatters.
__global__ __launch_bounds__(256) void rank_scatter_kernel(const u64* __restrict__ cand,
                                                           const float* __restrict__ deltas,
                                                           const float* __restrict__ iminfo,
                                                           float4* __restrict__ tb,
                                                           u64* __restrict__ vmask) {
    __shared__ u64 s[CAND_CAP];
    for (int j = threadIdx.x; j < CAND_CAP; j += 256) s[j] = cand[j];
    int half = threadIdx.x & 1;
    int i = blockIdx.x * 128 + (threadIdx.x >> 1);
    u64 k = cand[i];
    __syncthreads();
    const ulonglong2* sv = (const ulonglong2*)(s + half * (CAND_CAP / 2));
    unsigned int cnt = 0;
    #pragma unroll 8
    for (int j = 0; j < CAND_CAP / 4; ++j) {
        ulonglong2 v = sv[j];
        cnt += (v.x > k) ? 1u : 0u;
        cnt += (v.y > k) ? 1u : 0u;
    }
    cnt += __shfl_xor(cnt, 1);
    if (half == 0 && k != 0ull && cnt < TOPN) {
        unsigned int aidx = ~((unsigned int)k);
        int a = (int)(aidx % 9u);
        int cell = (int)(aidx / 9u);
        bool valid;
        float4 box = decode_box(a, cell, deltas, iminfo[0], iminfo[1], iminfo[2], &valid);
        tb[cnt] = box;
        if ((unsigned int)(k >> 32) != 0x007FFFFFu)
            atomicOr(&vmask[cnt >> 6], 1ull << (cnt & 63));
    }
}

// suppression bit-matrix, upper-triangle word-blocks only.
__global__ __launch_bounds__(64) void nms_matrix_kernel(const float4* __restrict__ tb,
                                                        u64* __restrict__ mat) {
    if (blockIdx.x < blockIdx.y) return;
    __shared__ float4 cb[64];
    int t = threadIdx.x;
    int c0 = blockIdx.x * 64;
    int col = c0 + t;
    cb[t] = (col < TOPN) ? tb[col] : make_float4(0.f, 0.f, 0.f, 0.f);
    __syncthreads();
    int row = blockIdx.y * 64 + t;
    if (row >= TOPN) return;
    float4 rb = tb[row];
    float rA = (rb.z - rb.x) * (rb.w - rb.y);
    u64 mask = 0ull;
    for (int c = 0; c < 64; ++c) {
        if (c0 + c >= TOPN) break;
        float4 b = cb[c];
        float lx = fmaxf(rb.x, b.x), ly = fmaxf(rb.y, b.y);
        float rx = fminf(rb.z, b.z), ry = fminf(rb.w, b.w);
        float iw = fmaxf(rx - lx, 0.f), ih = fmaxf(ry - ly, 0.f);
        float inter = iw * ih;
        float bA = (b.z - b.x) * (b.w - b.y);
        float iou = inter / ((rA + bA) - inter);
        if (iou > 0.7f) mask |= (1ull << c);   // NaN compares false, as in numpy
    }
    mat[(size_t)row * NWORDS + blockIdx.x] = mask;
}

// 64-bit readlane with wave-uniform index (v_readlane, ~10 cyc — much
// cheaper than ds_bpermute-based __shfl).
__device__ __forceinline__ u64 rdl64(u64 v, int l) {
    unsigned int lo = (unsigned int)__builtin_amdgcn_readlane((int)(unsigned int)v, l);
    unsigned int hi = (unsigned int)__builtin_amdgcn_readlane((int)(unsigned int)(v >> 32), l);
    return ((u64)hi << 32) | (u64)lo;
}

// single-wave greedy scan, 128-box chunks (47 sequential steps).
//  - diagonal 128x128 bit-block prefetched ONE CHUNK AHEAD into registers
//    (2x dwordx4 per lane, issued before the chunk's status is known)
//  - in-chunk greedy: wave-uniform ALU + 4 readlanes per kept box
//  - propagation: lane w owns removal words w / 64+w; per kept row one
//    coalesced-ish 8B load per word, batched 8 kept deep, one drain/chunk
__global__ __launch_bounds__(64) void nms_scan_kernel(const u64* __restrict__ mat,
                                                      const u64* __restrict__ vmask,
                                                      const float4* __restrict__ tb,
                                                      float* __restrict__ out) {
    int lane = threadIdx.x;
    u64 r0 = ~vmask[lane];
    u64 r1 = (lane < NWORDS - 64) ? ~vmask[64 + lane] : ~0ull;
    __shared__ int kept[POSTN];
    int cnt = 0;

    // prefetch chunk 0's diagonal block (rows lane & 64+lane, words 0..1)
    u64 a0, a1, b0, b1;
    {
        ulonglong2 vA = *(const ulonglong2*)(mat + (size_t)lane * NWORDS);
        ulonglong2 vB = *(const ulonglong2*)(mat + (size_t)(64 + lane) * NWORDS);
        a0 = vA.x; a1 = vA.y; b0 = vB.x; b1 = vB.y;
    }
    for (int c = 0; c < NCHUNK; ++c) {
        u64 na0 = 0, na1 = 0, nb0 = 0, nb1 = 0;
        if (c + 1 < NCHUNK) {   // rows (c+1)*128+lane(+64); row 6000..6015 pad reads land in ws slack
            const u64* pA = mat + (size_t)((c + 1) * 128 + lane) * NWORDS + 2 * (c + 1);
            const u64* pB = mat + (size_t)((c + 1) * 128 + 64 + lane) * NWORDS + 2 * (c + 1);
            ulonglong2 vA = *(const ulonglong2*)pA;
            ulonglong2 vB = *(const ulonglong2*)pB;
            na0 = vA.x; na1 = vA.y; nb0 = vB.x; nb1 = vB.y;
        }
        int w2 = 2 * c;
        u64 s0 = (w2 < 64) ? rdl64(r0, w2) : rdl64(r1, w2 - 64);
        u64 s1 = (w2 + 1 < 64) ? rdl64(r0, w2 + 1) : rdl64(r1, w2 + 1 - 64);
        if ((s0 & s1) != ~0ull) {
            int base = c * 128;
            u64 rem0 = s0, rem1 = s1, k0 = 0ull, k1 = 0ull;
            while (cnt < POSTN) {
                int b;
                if (~rem0) b = __ffsll((u64)~rem0) - 1;
                else if (~rem1) b = 64 + __ffsll((u64)~rem1) - 1;
                else break;
                if (lane == 0) kept[cnt] = base + b;
                ++cnt;
                u64 w0, w1;
                if (b < 64) {
                    w0 = rdl64(a0, b); w1 = rdl64(a1, b);
                    k0 |= 1ull << b; rem0 |= 1ull << b;
                } else {
                    int bb = b - 64;
                    w0 = rdl64(b0, bb); w1 = rdl64(b1, bb);
                    k1 |= 1ull << bb; rem1 |= 1ull << bb;
                }
                rem0 |= w0; rem1 |= w1;
            }
            if (cnt >= POSTN) break;   // propagation moot
            // propagate kept rows into lane-owned removal words, 8 per batch
            u64 f0 = 0ull, f1 = 0ull, m0 = k0, m1 = k1;
            while (m0 | m1) {
                int idxs[8];
                #pragma unroll
                for (int j = 0; j < 8; ++j) {
                    int b = -1;
                    if (m0) { b = __ffsll(m0) - 1; m0 &= m0 - 1; }
                    else if (m1) { b = 64 + __ffsll(m1) - 1; m1 &= m1 - 1; }
                    idxs[j] = b;
                }
                u64 v0[8], v1[8];
                #pragma unroll
                for (int j = 0; j < 8; ++j) {
                    v0[j] = 0ull; v1[j] = 0ull;
                    if (idxs[j] >= 0) {
                        const u64* row = mat + (size_t)(base + idxs[j]) * NWORDS;
                        v0[j] = row[lane];
                        if (lane < NWORDS - 64) v1[j] = row[64 + lane];
                    }
                }
                #pragma unroll
                for (int j = 0; j < 8; ++j) { f0 |= v0[j]; f1 |= v1[j]; }
            }
            r0 |= f0; r1 |= f1;
        }
        a0 = na0; a1 = na1; b0 = nb0; b1 = nb1;
    }

    for (int r = lane; r < POSTN; r += 64) {
        float4 b = make_float4(0.f, 0.f, 0.f, 0.f);
        if (r < cnt) b = tb[kept[r]];
        float* o = out + r * 5;
        o[0] = 0.f; o[1] = b.x; o[2] = b.y; o[3] = b.z; o[4] = b.w;
    }
}

// ---------------- host launcher ----------------
extern "C" void kernel_launch(void* const* d_in, const int* in_sizes, int n_in,
                              void* d_out, int out_size, void* d_ws, size_t ws_size,
                              hipStream_t stream) {
    const float* scores = (const float*)d_in[0];
    const float* deltas = (const float*)d_in[1];
    const float* iminfo = (const float*)d_in[2];
    float* out = (float*)d_out;

    char* ws = (char*)d_ws;
    // workspace layout (16B-aligned), total 5,833,536 bytes (mat padded to 6016 rows)
    unsigned int* keys   = (unsigned int*)(ws + 0);          // 221184*4  = 884736
    unsigned int* hist16 = (unsigned int*)(ws + 884736);     // 65536*4   = 262144
    unsigned int* state  = (unsigned int*)(ws + 1146880);    // 64
    u64*          cand   = (u64*)(ws + 1146944);             // 8192*8    = 65536
    float4*       tb     = (float4*)(ws + 1212480);          // 6016*16   = 96256
    u64*          vmask  = (u64*)(ws + 1308736);             // 768
    u64*          mat    = (u64*)(ws + 1309504);             // 6016*94*8 = 4524032

    const int NB = N_ANCH / 256;   // 864 exactly

    init_kernel<<<81, 256, 0, stream>>>((float4*)hist16, (float4*)vmask);
    decode_kernel<<<NB, 256, 0, stream>>>(scores, deltas, iminfo, keys, hist16);
    select16_kernel<<<1, 1024, 0, stream>>>(hist16, state);
    compact_kernel<<<NB, 256, 0, stream>>>(keys, state, cand);
    rank_scatter_kernel<<<CAND_CAP / 128, 256, 0, stream>>>(cand, deltas, iminfo, tb, vmask);
    nms_matrix_kernel<<<dim3(NWORDS, NWORDS), 64, 0, stream>>>(tb, mat);
    nms_scan_kernel<<<1, 64, 0, stream>>>(mat, vmask, tb, out);
}

// Round 6
// 248.977 us; speedup vs baseline: 1.4100x; 1.4100x over previous
//
#include <hip/hip_runtime.h>

// ---------------- problem constants ----------------
#define N_ANCH 221184      // H*W*A = 128*192*9
#define HW     24576       // H*W
#define Wd     192
#define AA     9
#define TOPN   6000
#define POSTN  300
#define CAND_CAP 8192
#define NWORDS 94          // ceil(6016/64) words of suppression bits
#define NCHUNK 47          // 6016 / 128

typedef unsigned long long u64;

// anchor widths/heights (== ws2/hs2 of the reference, exact small ints)
// ratio 0.5: 23x12 -> w {184,368,736}, h { 96,192,384}
// ratio 1.0: 16x16 -> w {128,256,512}, h {128,256,512}
// ratio 2.0: 11x22 -> w { 88,176,352}, h {176,352,704}
__device__ const float c_aw[9] = {184.f,368.f,736.f,128.f,256.f,512.f, 88.f,176.f,352.f};
__device__ const float c_ah[9] = { 96.f,192.f,384.f,128.f,256.f,512.f,176.f,352.f,704.f};

// shared box decode — used by decode_kernel AND rank_scatter so the FP
// sequence (and thus every bit of the box) is identical in both places.
// No-FMA contraction to match numpy's separate mul/add rounding.
__device__ __forceinline__ float4 decode_box(int a, int cell,
                                             const float* __restrict__ deltas,
                                             float info0, float info1, float info2,
                                             bool* valid) {
    int h = cell / Wd;
    int w = cell - h * Wd;
    const float* db = deltas + (size_t)(4 * a) * HW + cell;
    float dx = db[0];
    float dy = db[HW];
    float dw = db[2 * HW];
    float dh = db[3 * HW];
    dw = fminf(fmaxf(dw, -10.f), 10.f);
    dh = fminf(fmaxf(dh, -10.f), 10.f);

    float ww = c_aw[a], hh = c_ah[a];
    float cx = 16.f * (float)w + 8.f;   // exact
    float cy = 16.f * (float)h + 8.f;   // exact

    float pcx = __fadd_rn(__fmul_rn(dx, ww), cx);
    float pcy = __fadd_rn(__fmul_rn(dy, hh), cy);
    float pw  = __fmul_rn(expf(dw), ww);
    float ph  = __fmul_rn(expf(dh), hh);
    float hpw = __fmul_rn(0.5f, pw);
    float hph = __fmul_rn(0.5f, ph);
    float x1 = __fsub_rn(pcx, hpw);
    float x2 = __fadd_rn(pcx, hpw);
    float y1 = __fsub_rn(pcy, hph);
    float y2 = __fadd_rn(pcy, hph);

    float xmax = __fsub_rn(info1, 1.f);
    float ymax = __fsub_rn(info0, 1.f);
    x1 = fminf(fmaxf(x1, 0.f), xmax);
    x2 = fminf(fmaxf(x2, 0.f), xmax);
    y1 = fminf(fmaxf(y1, 0.f), ymax);
    y2 = fminf(fmaxf(y2, 0.f), ymax);

    float msz = __fmul_rn(16.f, info2);
    *valid = (__fadd_rn(__fsub_rn(x2, x1), 1.f) >= msz) &&
             (__fadd_rn(__fsub_rn(y2, y1), 1.f) >= msz);
    return make_float4(x1, y1, x2, y2);
}

// ---------------- init: zero hist256+state+cand (contiguous) + vmask ------
#define ZA_F4 4164    // (1024 + 64 + 65536) / 16
#define ZB_F4 48      // 768 / 16
__global__ __launch_bounds__(256) void init_kernel(float4* zA, float4* zB) {
    int t = blockIdx.x * 256 + threadIdx.x;
    float4 z = make_float4(0.f, 0.f, 0.f, 0.f);
    if (t < ZA_F4) zA[t] = z;
    else if (t < ZA_F4 + ZB_F4) zB[t - ZA_F4] = z;
}

// thread t maps to (a = t/HW, cell = t%HW) so reads of scores/deltas are
// coalesced. Writes the 32-bit ordered key; builds the top-BYTE histogram
// LDS-aggregated (256 global atomics per block — no contention bomb).
__global__ __launch_bounds__(256) void decode_kernel(const float* __restrict__ scores,
                                                     const float* __restrict__ deltas,
                                                     const float* __restrict__ iminfo,
                                                     unsigned int* __restrict__ keys,
                                                     unsigned int* __restrict__ hist256) {
    __shared__ unsigned int lh[256];
    lh[threadIdx.x] = 0u;
    __syncthreads();
    int t = blockIdx.x * 256 + threadIdx.x;
    int a = t / HW;
    int cell = t - a * HW;
    float score = scores[(AA + a) * HW + cell];
    bool valid;
    (void)decode_box(a, cell, deltas, iminfo[0], iminfo[1], iminfo[2], &valid);
    unsigned int sb = __float_as_uint(score);
    // flip to ordered-uint; invalid -> key of -inf (0x007FFFFF)
    unsigned int key = valid ? ((sb & 0x80000000u) ? ~sb : (sb | 0x80000000u))
                             : 0x007FFFFFu;
    keys[t] = key;
    atomicAdd(&lh[key >> 24], 1u);
    __syncthreads();
    if (lh[threadIdx.x]) atomicAdd(&hist256[threadIdx.x], lh[threadIdx.x]);
}

// one block, 1024 threads: (1) suffix-sum hist256 -> 8-bit prefix P + rank;
// (2) one pass over keys building second-byte hist for prefix-P keys, in
// per-wave LDS copies (contention /16); (3) suffix-sum -> 16-bit threshold.
// Also zeroes state[2] for compact.
__global__ __launch_bounds__(1024) void midselect_kernel(const unsigned int* __restrict__ keys,
                                                         const unsigned int* __restrict__ hist256,
                                                         unsigned int* __restrict__ state) {
    __shared__ unsigned int sfx[256];
    __shared__ unsigned int h2w[16][256];
    __shared__ unsigned int sP, sRank;
    int t = threadIdx.x;
    int wv = t >> 6;
    // zero per-wave hists
    for (int i = t; i < 16 * 256; i += 1024) ((unsigned int*)h2w)[i] = 0u;
    if (t < 256) sfx[t] = hist256[t];
    __syncthreads();
    for (int d = 1; d < 256; d <<= 1) {
        unsigned int v = 0u;
        if (t < 256 && t + d < 256) v = sfx[t + d];
        __syncthreads();
        if (t < 256) sfx[t] += v;
        __syncthreads();
    }
    if (t < 256) {
        unsigned int ge = sfx[t];
        unsigned int gt = (t < 255) ? sfx[t + 1] : 0u;
        if (ge >= TOPN && gt < TOPN) { sP = (unsigned int)t; sRank = TOPN - gt; }
    }
    __syncthreads();
    unsigned int P = sP, rank = sRank;
    // phase 2: second-byte hist of prefix-P keys
    const uint4* k4 = (const uint4*)keys;
    for (int i = t; i < N_ANCH / 4; i += 1024) {
        uint4 v = k4[i];
        if ((v.x >> 24) == P) atomicAdd(&h2w[wv][(v.x >> 16) & 0xFFu], 1u);
        if ((v.y >> 24) == P) atomicAdd(&h2w[wv][(v.y >> 16) & 0xFFu], 1u);
        if ((v.z >> 24) == P) atomicAdd(&h2w[wv][(v.z >> 16) & 0xFFu], 1u);
        if ((v.w >> 24) == P) atomicAdd(&h2w[wv][(v.w >> 16) & 0xFFu], 1u);
    }
    __syncthreads();
    // phase 3: reduce wave copies + suffix-sum
    if (t < 256) {
        unsigned int s = 0;
        #pragma unroll
        for (int wvi = 0; wvi < 16; ++wvi) s += h2w[wvi][t];
        sfx[t] = s;
    }
    __syncthreads();
    for (int d = 1; d < 256; d <<= 1) {
        unsigned int v = 0u;
        if (t < 256 && t + d < 256) v = sfx[t + d];
        __syncthreads();
        if (t < 256) sfx[t] += v;
        __syncthreads();
    }
    if (t < 256) {
        unsigned int ge = sfx[t];
        unsigned int gt = (t < 255) ? sfx[t + 1] : 0u;
        if (ge >= rank && gt < rank) {
            state[0] = (P << 24) | ((unsigned int)t << 16);
            state[2] = 0u;
        }
    }
}

// take all keys >= T (boundary bucket fully included; cc ~6000+bucket < 8192)
__global__ __launch_bounds__(256) void compact_kernel(const unsigned int* __restrict__ keys,
                                                      unsigned int* __restrict__ state,
                                                      u64* __restrict__ cand) {
    int t = blockIdx.x * 256 + threadIdx.x;
    unsigned int k = keys[t];
    unsigned int T = state[0];
    if (k >= T) {
        unsigned int pos = atomicAdd(&state[2], 1u);
        if (pos < CAND_CAP) {
            int a = t / HW;
            int cell = t - a * HW;
            unsigned int aidx = (unsigned int)(cell * 9 + a);  // reference anchor index
            cand[pos] = ((u64)k << 32) | (u64)(~aidx);
        }
    }
}

// fused exact-rank + scatter. rank[i] = #{j : key_j > key_i}; keys distinct
// (index in low bits) -> rank == sorted position (score desc, index asc —
// lax.top_k order). 256 blocks, 8 threads per i (32 i's/block); j-loop is
// interleaved (jj = part + 8k) so each wave-instruction reads 8 CONSECUTIVE
// ulonglong2s (conflict-free, broadcast across the 8 i-groups).
__global__ __launch_bounds__(256) void rank_scatter_kernel(const u64* __restrict__ cand,
                                                           const float* __restrict__ deltas,
                                                           const float* __restrict__ iminfo,
                                                           float4* __restrict__ tb,
                                                           u64* __restrict__ vmask) {
    __shared__ u64 s[CAND_CAP];
    for (int j = threadIdx.x; j < CAND_CAP; j += 256) s[j] = cand[j];
    int part = threadIdx.x & 7;
    int i = blockIdx.x * 32 + (threadIdx.x >> 3);
    u64 k = cand[i];
    __syncthreads();
    const ulonglong2* sv = (const ulonglong2*)s;
    unsigned int cnt = 0;
    #pragma unroll 8
    for (int jj = part; jj < CAND_CAP / 2; jj += 8) {
        ulonglong2 v = sv[jj];
        cnt += (v.x > k) ? 1u : 0u;
        cnt += (v.y > k) ? 1u : 0u;
    }
    cnt += __shfl_xor(cnt, 1);
    cnt += __shfl_xor(cnt, 2);
    cnt += __shfl_xor(cnt, 4);
    if (part == 0 && k != 0ull && cnt < TOPN) {
        unsigned int aidx = ~((unsigned int)k);
        int a = (int)(aidx % 9u);
        int cell = (int)(aidx / 9u);
        bool valid;
        float4 box = decode_box(a, cell, deltas, iminfo[0], iminfo[1], iminfo[2], &valid);
        tb[cnt] = box;
        if ((unsigned int)(k >> 32) != 0x007FFFFFu)
            atomicOr(&vmask[cnt >> 6], 1ull << (cnt & 63));
    }
}

// suppression bit-matrix, upper-triangle word-blocks only.
__global__ __launch_bounds__(64) void nms_matrix_kernel(const float4* __restrict__ tb,
                                                        u64* __restrict__ mat) {
    if (blockIdx.x < blockIdx.y) return;
    __shared__ float4 cb[64];
    int t = threadIdx.x;
    int c0 = blockIdx.x * 64;
    int col = c0 + t;
    cb[t] = (col < TOPN) ? tb[col] : make_float4(0.f, 0.f, 0.f, 0.f);
    __syncthreads();
    int row = blockIdx.y * 64 + t;
    if (row >= TOPN) return;
    float4 rb = tb[row];
    float rA = (rb.z - rb.x) * (rb.w - rb.y);
    u64 mask = 0ull;
    for (int c = 0; c < 64; ++c) {
        if (c0 + c >= TOPN) break;
        float4 b = cb[c];
        float lx = fmaxf(rb.x, b.x), ly = fmaxf(rb.y, b.y);
        float rx = fminf(rb.z, b.z), ry = fminf(rb.w, b.w);
        float iw = fmaxf(rx - lx, 0.f), ih = fmaxf(ry - ly, 0.f);
        float inter = iw * ih;
        float bA = (b.z - b.x) * (b.w - b.y);
        float iou = inter / ((rA + bA) - inter);
        if (iou > 0.7f) mask |= (1ull << c);   // NaN compares false, as in numpy
    }
    mat[(size_t)row * NWORDS + blockIdx.x] = mask;
}

// 64-bit readlane with wave-uniform index (v_readlane — much cheaper than
// ds_bpermute-based __shfl).
__device__ __forceinline__ u64 rdl64(u64 v, int l) {
    unsigned int lo = (unsigned int)__builtin_amdgcn_readlane((int)(unsigned int)v, l);
    unsigned int hi = (unsigned int)__builtin_amdgcn_readlane((int)(unsigned int)(v >> 32), l);
    return ((u64)hi << 32) | (u64)lo;
}

// single-wave greedy scan, 128-box chunks (47 sequential steps).
//  - diagonal 128x128 bit-block prefetched ONE CHUNK AHEAD into registers
//  - in-chunk greedy: wave-uniform ALU + 4 readlanes per kept box
//  - propagation: lane w owns removal words w / 64+w; batched 8 kept deep
__global__ __launch_bounds__(64) void nms_scan_kernel(const u64* __restrict__ mat,
                                                      const u64* __restrict__ vmask,
                                                      const float4* __restrict__ tb,
                                                      float* __restrict__ out) {
    int lane = threadIdx.x;
    u64 r0 = ~vmask[lane];
    u64 r1 = (lane < NWORDS - 64) ? ~vmask[64 + lane] : ~0ull;
    __shared__ int kept[POSTN];
    int cnt = 0;

    u64 a0, a1, b0, b1;
    {
        ulonglong2 vA = *(const ulonglong2*)(mat + (size_t)lane * NWORDS);
        ulonglong2 vB = *(const ulonglong2*)(mat + (size_t)(64 + lane) * NWORDS);
        a0 = vA.x; a1 = vA.y; b0 = vB.x; b1 = vB.y;
    }
    for (int c = 0; c < NCHUNK; ++c) {
        u64 na0 = 0, na1 = 0, nb0 = 0, nb1 = 0;
        if (c + 1 < NCHUNK) {
            const u64* pA = mat + (size_t)((c + 1) * 128 + lane) * NWORDS + 2 * (c + 1);
            const u64* pB = mat + (size_t)((c + 1) * 128 + 64 + lane) * NWORDS + 2 * (c + 1);
            ulonglong2 vA = *(const ulonglong2*)pA;
            ulonglong2 vB = *(const ulonglong2*)pB;
            na0 = vA.x; na1 = vA.y; nb0 = vB.x; nb1 = vB.y;
        }
        int w2 = 2 * c;
        u64 s0 = (w2 < 64) ? rdl64(r0, w2) : rdl64(r1, w2 - 64);
        u64 s1 = (w2 + 1 < 64) ? rdl64(r0, w2 + 1) : rdl64(r1, w2 + 1 - 64);
        if ((s0 & s1) != ~0ull) {
            int base = c * 128;
            u64 rem0 = s0, rem1 = s1, k0 = 0ull, k1 = 0ull;
            while (cnt < POSTN) {
                int b;
                if (~rem0) b = __ffsll((u64)~rem0) - 1;
                else if (~rem1) b = 64 + __ffsll((u64)~rem1) - 1;
                else break;
                if (lane == 0) kept[cnt] = base + b;
                ++cnt;
                u64 w0, w1;
                if (b < 64) {
                    w0 = rdl64(a0, b); w1 = rdl64(a1, b);
                    k0 |= 1ull << b; rem0 |= 1ull << b;
                } else {
                    int bb = b - 64;
                    w0 = rdl64(b0, bb); w1 = rdl64(b1, bb);
                    k1 |= 1ull << bb; rem1 |= 1ull << bb;
                }
                rem0 |= w0; rem1 |= w1;
            }
            if (cnt >= POSTN) break;
            u64 f0 = 0ull, f1 = 0ull, m0 = k0, m1 = k1;
            while (m0 | m1) {
                int idxs[8];
                #pragma unroll
                for (int j = 0; j < 8; ++j) {
                    int b = -1;
                    if (m0) { b = __ffsll(m0) - 1; m0 &= m0 - 1; }
                    else if (m1) { b = 64 + __ffsll(m1) - 1; m1 &= m1 - 1; }
                    idxs[j] = b;
                }
                u64 v0[8], v1[8];
                #pragma unroll
                for (int j = 0; j < 8; ++j) {
                    v0[j] = 0ull; v1[j] = 0ull;
                    if (idxs[j] >= 0) {
                        const u64* row = mat + (size_t)(base + idxs[j]) * NWORDS;
                        v0[j] = row[lane];
                        if (lane < NWORDS - 64) v1[j] = row[64 + lane];
                    }
                }
                #pragma unroll
                for (int j = 0; j < 8; ++j) { f0 |= v0[j]; f1 |= v1[j]; }
            }
            r0 |= f0; r1 |= f1;
        }
        a0 = na0; a1 = na1; b0 = nb0; b1 = nb1;
    }

    for (int r = lane; r < POSTN; r += 64) {
        float4 b = make_float4(0.f, 0.f, 0.f, 0.f);
        if (r < cnt) b = tb[kept[r]];
        float* o = out + r * 5;
        o[0] = 0.f; o[1] = b.x; o[2] = b.y; o[3] = b.z; o[4] = b.w;
    }
}

// ---------------- host launcher ----------------
extern "C" void kernel_launch(void* const* d_in, const int* in_sizes, int n_in,
                              void* d_out, int out_size, void* d_ws, size_t ws_size,
                              hipStream_t stream) {
    const float* scores = (const float*)d_in[0];
    const float* deltas = (const float*)d_in[1];
    const float* iminfo = (const float*)d_in[2];
    float* out = (float*)d_out;

    char* ws = (char*)d_ws;
    // workspace layout (16B-aligned), total 5,572,416 bytes
    unsigned int* keys    = (unsigned int*)(ws + 0);          // 221184*4  = 884736
    unsigned int* hist256 = (unsigned int*)(ws + 884736);     // 256*4     = 1024
    unsigned int* state   = (unsigned int*)(ws + 885760);     // 64
    u64*          cand    = (u64*)(ws + 885824);              // 8192*8    = 65536
    float4*       tb      = (float4*)(ws + 951360);           // 6016*16   = 96256
    u64*          vmask   = (u64*)(ws + 1047616);             // 768
    u64*          mat     = (u64*)(ws + 1048384);             // 6016*94*8 = 4524032

    const int NB = N_ANCH / 256;   // 864 exactly

    init_kernel<<<17, 256, 0, stream>>>((float4*)hist256, (float4*)vmask);
    decode_kernel<<<NB, 256, 0, stream>>>(scores, deltas, iminfo, keys, hist256);
    midselect_kernel<<<1, 1024, 0, stream>>>(keys, hist256, state);
    compact_kernel<<<NB, 256, 0, stream>>>(keys, state, cand);
    rank_scatter_kernel<<<CAND_CAP / 32, 256, 0, stream>>>(cand, deltas, iminfo, tb, vmask);
    nms_matrix_kernel<<<dim3(NWORDS, NWORDS), 64, 0, stream>>>(tb, mat);
    nms_scan_kernel<<<1, 64, 0, stream>>>(mat, vmask, tb, out);
}